// Round 1
// baseline (78.528 us; speedup 1.0000x reference)
//
#include <hip/hip_runtime.h>

// TripletLoss semi-hard mining, B=512, D=256, fp32.
// Kernel 1: 256 blocks x 256 thr; block b owns anchors {2b, 2b+1}.
//   Phase 1: stream emb in 32-row LDS tiles; compute dot(e_j, e_k) for both
//            anchors + sq-norm(e_k) via dim-octant partials; pd = max(sq_j-2ab+sq_k,0).
//   Phase 2: neg_inside (max over negatives, init 0 == rowmin), positive list,
//            per-positive wave min-reduce over valid semi-hard negatives.
//   Writes per-block loss sum + positive count to d_ws.
// Kernel 2: single block reduces 256 partials, out = sum/count.

__device__ inline float wave_max(float v){
  #pragma unroll
  for (int o = 32; o > 0; o >>= 1) v = fmaxf(v, __shfl_xor(v, o));
  return v;
}
__device__ inline float wave_min(float v){
  #pragma unroll
  for (int o = 32; o > 0; o >>= 1) v = fminf(v, __shfl_xor(v, o));
  return v;
}
__device__ inline float wave_sum(float v){
  #pragma unroll
  for (int o = 32; o > 0; o >>= 1) v += __shfl_xor(v, o);
  return v;
}

__global__ __launch_bounds__(256) void triplet_main(
    const float* __restrict__ emb, const int* __restrict__ labels,
    float* __restrict__ pl, float* __restrict__ pc)
{
  __shared__ float4 tile[32][65];      // 32 k-rows x 64 float4, +1 f4 pad
  __shared__ float part[8][96];        // dim-octant partials: [q][qty*32+klocal]
  __shared__ float pdrow[2][512];      // dot, then pd, per anchor
  __shared__ float sqarr[512];
  __shared__ int   lab[512];
  __shared__ int   plist[2][512];
  __shared__ int   pcount[2];
  __shared__ float redm[4][4];
  __shared__ float scal[2];

  const int t   = threadIdx.x;
  const int ja0 = blockIdx.x * 2, ja1 = ja0 + 1;
  const int kl  = t & 31;              // k within tile
  const int q   = t >> 5;              // dim octant (32 dims = 8 float4)
  const int lane = t & 63, wid = t >> 6;
  const float4* embf4 = reinterpret_cast<const float4*>(emb);

  lab[t]       = labels[t];
  lab[t + 256] = labels[t + 256];
  if (t < 2) pcount[t] = 0;

  // anchor fragments for this thread's dim octant, kept in registers
  float4 ej0[8], ej1[8];
  #pragma unroll
  for (int i = 0; i < 8; ++i){
    ej0[i] = embf4[ja0 * 64 + q * 8 + i];
    ej1[i] = embf4[ja1 * 64 + q * 8 + i];
  }

  for (int ti = 0; ti < 16; ++ti){
    __syncthreads();                   // tile buffer reuse
    const int kbase = ti * 32;
    #pragma unroll
    for (int j = 0; j < 8; ++j){       // stage 32x256 f32, coalesced
      int idx = t + j * 256;
      int r = idx >> 6, c = idx & 63;
      tile[r][c] = embf4[(kbase + r) * 64 + c];
    }
    __syncthreads();
    float a0 = 0.f, a1 = 0.f, as = 0.f;
    #pragma unroll
    for (int i = 0; i < 8; ++i){
      float4 e = tile[kl][q * 8 + i];
      float4 x = ej0[i], y = ej1[i];
      a0 += e.x*x.x + e.y*x.y + e.z*x.z + e.w*x.w;
      a1 += e.x*y.x + e.y*y.y + e.z*y.z + e.w*y.w;
      as += e.x*e.x + e.y*e.y + e.z*e.z + e.w*e.w;
    }
    part[q][kl]      = a0;
    part[q][32 + kl] = a1;
    part[q][64 + kl] = as;
    __syncthreads();
    if (t < 96){                       // combine 8 octants
      int qty = t >> 5, k2 = t & 31;
      float s = 0.f;
      #pragma unroll
      for (int qq = 0; qq < 8; ++qq) s += part[qq][qty * 32 + k2];
      int kg = kbase + k2;
      if (qty == 0)      pdrow[0][kg] = s;
      else if (qty == 1) pdrow[1][kg] = s;
      else               sqarr[kg]    = s;
    }
  }
  __syncthreads();

  // pd = max(sq_j - 2ab + sq_k, 0), diagonal forced to 0 (as reference)
  const float sq0 = sqarr[ja0], sq1 = sqarr[ja1];
  #pragma unroll
  for (int j = 0; j < 2; ++j){
    int k = t + j * 256;
    float sk = sqarr[k];
    float d0 = fmaxf(sq0 - 2.f * pdrow[0][k] + sk, 0.f);
    float d1 = fmaxf(sq1 - 2.f * pdrow[1][k] + sk, 0.f);
    pdrow[0][k] = (k == ja0) ? 0.f : d0;
    pdrow[1][k] = (k == ja1) ? 0.f : d1;
  }
  __syncthreads();

  // neg_inside = max over negatives (rowmin == 0), and positive lists
  const int lj0 = lab[ja0], lj1 = lab[ja1];
  float ni0 = 0.f, ni1 = 0.f;
  #pragma unroll
  for (int j = 0; j < 2; ++j){
    int k = t + j * 256;
    float p0 = pdrow[0][k], p1 = pdrow[1][k];
    int lk = lab[k];
    if (lk != lj0) ni0 = fmaxf(ni0, p0);
    if (lk != lj1) ni1 = fmaxf(ni1, p1);
    if (k != ja0 && lk == lj0) plist[0][atomicAdd(&pcount[0], 1)] = k;
    if (k != ja1 && lk == lj1) plist[1][atomicAdd(&pcount[1], 1)] = k;
  }
  ni0 = wave_max(ni0); ni1 = wave_max(ni1);
  if (lane == 0){ redm[wid][0] = ni0; redm[wid][1] = ni1; }
  __syncthreads();
  if (t == 0){
    scal[0] = fmaxf(fmaxf(redm[0][0], redm[1][0]), fmaxf(redm[2][0], redm[3][0]));
    scal[1] = fmaxf(fmaxf(redm[0][1], redm[1][1]), fmaxf(redm[2][1], redm[3][1]));
  }
  __syncthreads();

  // semi-hard mining: one wave per positive
  float wacc = 0.f;
  #pragma unroll 1
  for (int a = 0; a < 2; ++a){
    const int   P       = pcount[a];
    const int   lj      = a ? lj1 : lj0;
    const float ninside = scal[a];
    const float* pda    = pdrow[a];
    for (int p = wid; p < P; p += 4){
      int   i   = plist[a][p];
      float tiv = pda[i];
      float vmin = 3.402823466e38f;
      #pragma unroll
      for (int m = 0; m < 8; ++m){
        int k = lane + m * 64;
        float pk = pda[k];
        if (lab[k] != lj && pk > tiv) vmin = fminf(vmin, pk);
      }
      vmin = wave_min(vmin);
      float semi = (vmin < 3.0e38f) ? vmin : ninside;  // mask_final fallback
      float c = fmaxf(1.0f + tiv - semi, 0.0f);
      if (lane == 0) wacc += c;
    }
  }
  wacc = wave_sum(wacc);
  if (lane == 0) redm[wid][2] = wacc;
  __syncthreads();
  if (t == 0){
    pl[blockIdx.x] = redm[0][2] + redm[1][2] + redm[2][2] + redm[3][2];
    pc[blockIdx.x] = (float)(pcount[0] + pcount[1]);
  }
}

__global__ __launch_bounds__(256) void triplet_final(
    const float* __restrict__ pl, const float* __restrict__ pc,
    float* __restrict__ out)
{
  int t = threadIdx.x;
  float s = pl[t];
  float c = pc[t];
  s = wave_sum(s);
  c = wave_sum(c);
  __shared__ float rs[4], rc[4];
  int wid = t >> 6, lane = t & 63;
  if (lane == 0){ rs[wid] = s; rc[wid] = c; }
  __syncthreads();
  if (t == 0)
    out[0] = (rs[0] + rs[1] + rs[2] + rs[3]) / (rc[0] + rc[1] + rc[2] + rc[3]);
}

extern "C" void kernel_launch(void* const* d_in, const int* in_sizes, int n_in,
                              void* d_out, int out_size, void* d_ws, size_t ws_size,
                              hipStream_t stream) {
  const float* emb    = (const float*)d_in[0];
  const int*   labels = (const int*)d_in[1];
  float* out = (float*)d_out;
  float* pl  = (float*)d_ws;        // [256] per-block loss sums
  float* pc  = pl + 256;            // [256] per-block positive counts
  triplet_main<<<256, 256, 0, stream>>>(emb, labels, pl, pc);
  triplet_final<<<1, 256, 0, stream>>>(pl, pc, out);
}

// Round 2
// 71.526 us; speedup vs baseline: 1.0979x; 1.0979x over previous
//
#include <hip/hip_runtime.h>

// TripletLoss semi-hard, B=512, D=256, fp32.
// K1 pd_gemm: 256 blocks (16x16 grid of 32x32 tiles), 256 thr.
//   Stage A-rows/B-rows [32][256] in LDS (stride 260 floats -> 2-way-max bank
//   aliasing, free). Thread computes 2x2 outputs (rows t&15/+16, cols t>>4/+16):
//   per 4 k-steps = 4 ds_read_b128 + 16 FMA. sq-norms computed from global in
//   parallel with staging. Epilogue: pd = max(sq_r+sq_c-2*dot,0), diag zeroed,
//   LDS-transposed for coalesced float4 stores. Block 0 zeroes the accumulators.
// K2 mining: 128 blocks x 256 thr, one wave per anchor. pd row + labels live in
//   registers (8/lane); semi-hard min via ballot over positives + shuffle
//   broadcast + 64-lane butterfly min. Block partials -> device atomicAdd;
//   last block (ticket) computes loss = sum/count.

#define BN 512
#define DF4 64

__device__ inline float wave_max64(float v){
  #pragma unroll
  for (int o = 32; o > 0; o >>= 1) v = fmaxf(v, __shfl_xor(v, o));
  return v;
}
__device__ inline float wave_min64(float v){
  #pragma unroll
  for (int o = 32; o > 0; o >>= 1) v = fminf(v, __shfl_xor(v, o));
  return v;
}

__global__ __launch_bounds__(256) void pd_gemm(
    const float* __restrict__ emb, float* __restrict__ pd, float* __restrict__ acc)
{
  __shared__ float As[32][260];   // stride 260: banks (4r+4k)%32, 2-way max (free)
  __shared__ float Bs[32][260];
  __shared__ float sqA[32], sqB[32];
  __shared__ float outt[32][36];  // store-transpose staging, 16B-aligned rows

  const int t  = threadIdx.x;
  const int bi = blockIdx.x & 15, bj = blockIdx.x >> 4;
  const int R0 = bi * 32, C0 = bj * 32;
  const float4* ef4 = reinterpret_cast<const float4*>(emb);

  if (blockIdx.x == 0 && t == 0){ acc[0] = 0.f; acc[1] = 0.f; ((int*)acc)[2] = 0; }

  // stage both tiles, coalesced 1KB/instr
  #pragma unroll
  for (int j = 0; j < 8; ++j){
    int idx = t + j * 256;
    int r = idx >> 6, c = idx & 63;
    float4 va = ef4[(R0 + r) * DF4 + c];
    float4 vb = ef4[(C0 + r) * DF4 + c];
    *(float4*)&As[r][c * 4] = va;
    *(float4*)&Bs[r][c * 4] = vb;
  }
  // sq norms straight from global (L2-hot), overlaps staging latency
  {
    int half = t >> 7, u = t & 127;
    int r = u >> 2, part = u & 3;
    int base = ((half ? C0 : R0) + r) * DF4 + part * 16;
    float s = 0.f;
    #pragma unroll
    for (int i = 0; i < 16; ++i){
      float4 v = ef4[base + i];
      s += v.x*v.x + v.y*v.y + v.z*v.z + v.w*v.w;
    }
    s += __shfl_xor(s, 1); s += __shfl_xor(s, 2);
    if (part == 0){ if (half) sqB[r] = s; else sqA[r] = s; }
  }
  __syncthreads();

  const int r0 = t & 15, r1 = r0 + 16;
  const int c0 = t >> 4, c1 = c0 + 16;
  float a00 = 0.f, a01 = 0.f, a10 = 0.f, a11 = 0.f;
  #pragma unroll 8
  for (int kg = 0; kg < 64; ++kg){
    float4 A0 = *(const float4*)&As[r0][kg * 4];
    float4 A1 = *(const float4*)&As[r1][kg * 4];
    float4 B0 = *(const float4*)&Bs[c0][kg * 4];
    float4 B1 = *(const float4*)&Bs[c1][kg * 4];
    a00 += A0.x*B0.x + A0.y*B0.y + A0.z*B0.z + A0.w*B0.w;
    a01 += A0.x*B1.x + A0.y*B1.y + A0.z*B1.z + A0.w*B1.w;
    a10 += A1.x*B0.x + A1.y*B0.y + A1.z*B0.z + A1.w*B0.w;
    a11 += A1.x*B1.x + A1.y*B1.y + A1.z*B1.z + A1.w*B1.w;
  }

  const float sr0 = sqA[r0], sr1 = sqA[r1];
  const float sc0 = sqB[c0], sc1 = sqB[c1];
  float p00 = fmaxf(sr0 + sc0 - 2.f * a00, 0.f);
  float p01 = fmaxf(sr0 + sc1 - 2.f * a01, 0.f);
  float p10 = fmaxf(sr1 + sc0 - 2.f * a10, 0.f);
  float p11 = fmaxf(sr1 + sc1 - 2.f * a11, 0.f);
  if (bi == bj){                       // zero the diagonal (reference semantics)
    if (r0 == c0) p00 = 0.f;
    if (r0 == c1) p01 = 0.f;
    if (r1 == c0) p10 = 0.f;
    if (r1 == c1) p11 = 0.f;
  }
  outt[r0][c0] = p00; outt[r0][c1] = p01;
  outt[r1][c0] = p10; outt[r1][c1] = p11;
  __syncthreads();

  int rr = t >> 3, cc = t & 7;         // coalesced float4 stores, 128B/row-seg
  float4 v = *(float4*)&outt[rr][cc * 4];
  *(float4*)&pd[(R0 + rr) * BN + C0 + cc * 4] = v;
}

__global__ __launch_bounds__(256) void mining(
    const float* __restrict__ pd, const int* __restrict__ labels,
    float* __restrict__ acc, float* __restrict__ out)
{
  __shared__ float wls[4], wcs[4];
  const int t = threadIdx.x, lane = t & 63, wid = t >> 6;
  const int j  = blockIdx.x * 4 + wid;          // one anchor per wave
  const int lj = labels[j];

  const float4* prow = reinterpret_cast<const float4*>(pd + (size_t)j * BN);
  const int4*   lrow = reinterpret_cast<const int4*>(labels);
  float4 p0 = prow[lane * 2], p1 = prow[lane * 2 + 1];
  int4   l0 = lrow[lane * 2], l1 = lrow[lane * 2 + 1];
  float pk[8] = {p0.x, p0.y, p0.z, p0.w, p1.x, p1.y, p1.z, p1.w};
  int   lk[8] = {l0.x, l0.y, l0.z, l0.w, l1.x, l1.y, l1.z, l1.w};
  const int kbase = lane * 8;

  // negatives_inside: max over adj_not (rowmin filler == 0 since diag is 0)
  float ninside = 0.f;
  #pragma unroll
  for (int m = 0; m < 8; ++m)
    if (lk[m] != lj) ninside = fmaxf(ninside, pk[m]);
  ninside = wave_max64(ninside);

  float lsum = 0.f; int pcnt = 0;
  #pragma unroll
  for (int m = 0; m < 8; ++m){
    unsigned long long bal = __ballot(lk[m] == lj && (kbase + m) != j);
    while (bal){
      int L = (int)__ffsll((unsigned long long)bal) - 1;
      bal &= bal - 1;
      float tiv = __shfl(pk[m], L);             // pd[j][i], broadcast
      float vmin = 3.402823466e38f;
      #pragma unroll
      for (int mm = 0; mm < 8; ++mm)
        if (lk[mm] != lj && pk[mm] > tiv) vmin = fminf(vmin, pk[mm]);
      vmin = wave_min64(vmin);
      float semi = (vmin < 3.0e38f) ? vmin : ninside;  // mask_final fallback
      lsum += fmaxf(1.0f + tiv - semi, 0.f);
      ++pcnt;                                   // identical on all lanes
    }
  }

  if (lane == 0){ wls[wid] = lsum; wcs[wid] = (float)pcnt; }
  __syncthreads();
  if (t == 0){
    float bl = wls[0] + wls[1] + wls[2] + wls[3];
    float bc = wcs[0] + wcs[1] + wcs[2] + wcs[3];
    atomicAdd(&acc[0], bl);
    atomicAdd(&acc[1], bc);
    __threadfence();
    int tk = atomicAdd((int*)acc + 2, 1);
    if (tk == 127){                             // last block finalizes
      __threadfence();
      float tot = atomicAdd(&acc[0], 0.f);      // device-scope coherent read
      float cnt = atomicAdd(&acc[1], 0.f);
      out[0] = tot / cnt;
    }
  }
}

extern "C" void kernel_launch(void* const* d_in, const int* in_sizes, int n_in,
                              void* d_out, int out_size, void* d_ws, size_t ws_size,
                              hipStream_t stream) {
  const float* emb    = (const float*)d_in[0];
  const int*   labels = (const int*)d_in[1];
  float* out = (float*)d_out;
  float* pdw = (float*)d_ws;                 // [512*512] pd matrix
  float* acc = pdw + BN * BN;                // [0]=loss, [1]=count, [2]=ticket
  pd_gemm<<<256, 256, 0, stream>>>(emb, pdw, acc);
  mining<<<128, 256, 0, stream>>>(pdw, labels, acc, out);
}